// Round 1
// 271.184 us; speedup vs baseline: 1.0470x; 1.0470x over previous
//
#include <hip/hip_runtime.h>
#include <stdint.h>

typedef int int32x4 __attribute__((ext_vector_type(4)));

#define HW_        3136          // 56*56
#define CHW_       802816        // 256*3136
#define HP_        58
#define WP_        58
#define PLANE_PIX  107648ull     // 32*58*58 pixels per 16-channel plane
#define PLANE_B    (PLANE_PIX*16)        // 1,722,368 B
#define QXP_BYTES  (16ull*PLANE_B)       // 27,557,888 B : [cq][b][hp][wp][16]
#define QWT_BYTES  (9ull*16*256*16)      // 589,824  B : [kk][cq][o][16]

__device__ __forceinline__ signed char quant8(float v, float s) {
    float t = v * s;
    t = fmaxf(t, -128.0f);                 // clip FIRST (round(clip(...)))
    t = fminf(t, 127.0f);
    return (signed char)(int)rintf(t);     // half-to-even == jnp.round
}

// ---------------- halo rows: zero padded rows hp=0 and hp=57 (all b, cq) ----------------
__global__ __launch_bounds__(256) void halo_rows_kernel(signed char* __restrict__ qxp2) {
    int idx = blockIdx.x*256 + threadIdx.x;     // 16*32*2*58 = 59392 chunks
    if (idx < 16*32*2*58) {
        int cq = idx / (32*2*58);
        int r  = idx % (32*2*58);
        int b  = r / (2*58);
        int t  = r % (2*58);
        int hp = (t / 58) * (HP_-1);
        int wp = t % 58;
        *(int32x4*)(qxp2 + ((size_t)cq*PLANE_PIX + (size_t)(b*HP_+hp)*WP_ + wp)*16)
            = (int32x4){0,0,0,0};
    }
}

// ---------------- weight quantize: w[o][c][3][3] -> qwT2[kk][cq][o][16] ----------------
__global__ __launch_bounds__(256) void quant_w_kernel(
    const float* __restrict__ wgt, const float* __restrict__ sw,
    signed char* __restrict__ qwT2)
{
    __shared__ __align__(16) signed char lw[9*272];
    const int o = blockIdx.x, c = threadIdx.x;
    const float s = sw[o];
    const float* wp = wgt + ((size_t)o*256 + c)*9;
    #pragma unroll
    for (int kk = 0; kk < 9; ++kk)
        lw[kk*272 + c] = quant8(wp[kk], s);
    __syncthreads();
    if (c < 144) {
        int kk = c / 16, cq = c - kk*16;
        int32x4 v = *(const int32x4*)&lw[kk*272 + cq*16];
        *(int32x4*)(qwT2 + ((size_t)(kk*16 + cq)*256 + o)*16) = v;
    }
}

// ---------------- activation quantize: x NCHW fp32 -> qxp2[cq][b][hp][wp][16] ----------------
// LDS-free: thread <-> (cq-group, w). Coalesced scalar reads, contiguous 16B stores.
__global__ __launch_bounds__(256) void quant_x_kernel(
    const float* __restrict__ x, const float* __restrict__ sx,
    signed char* __restrict__ qxp2)
{
    const int tid = threadIdx.x;
    const int bh = blockIdx.x;                // 32*56
    const int b = bh / 56, h = bh % 56;
    const float s = sx[0];
    if (tid < 224) {
        const int w  = tid % 56;
        const int cg = tid / 56;              // 0..3 -> cq = cg*4+k
        const size_t xrow = (size_t)b*CHW_ + (size_t)h*56 + w;
        const size_t pb = ((size_t)(b*HP_ + h + 1)*WP_ + 1 + w)*16;
        #pragma unroll
        for (int k = 0; k < 4; ++k) {
            const int cq = cg*4 + k;
            const float* xp = x + xrow + (size_t)(cq*16)*HW_;
            int pk[4];
            #pragma unroll
            for (int g = 0; g < 4; ++g) {
                int b0 = (unsigned char)quant8(xp[(size_t)(4*g+0)*HW_], s);
                int b1 = (unsigned char)quant8(xp[(size_t)(4*g+1)*HW_], s);
                int b2 = (unsigned char)quant8(xp[(size_t)(4*g+2)*HW_], s);
                int b3 = (unsigned char)quant8(xp[(size_t)(4*g+3)*HW_], s);
                pk[g] = b0 | (b1 << 8) | (b2 << 16) | (b3 << 24);
            }
            *(int32x4*)(qxp2 + (size_t)cq*PLANE_B + pb) = (int32x4){pk[0],pk[1],pk[2],pk[3]};
        }
    } else {
        // w-halo of this padded row: w = 0 and 57, all 16 cq
        int t2 = tid - 224;                   // 0..31
        int cq = t2 >> 1, wp = (t2 & 1) * (WP_-1);
        const size_t rowpix = (size_t)(b*HP_ + h + 1)*WP_;
        *(int32x4*)(qxp2 + ((size_t)cq*PLANE_PIX + rowpix + wp)*16) = (int32x4){0,0,0,0};
    }
}

// ---------------- int8 implicit-GEMM conv ----------------
// A = qwT2 (M=o), B = qxp2 (N=pixels), K = 9*256. Tile 128x128, BK=128.
// Double-buffered LDS (2 x 32KB), counted vmcnt(8) + raw s_barrier so the
// next step's 8 global_load_lds stay in flight across the whole compute phase.
__device__ __forceinline__ void load16_lds(const void* g, void* l) {
    __builtin_amdgcn_global_load_lds(
        (const unsigned int*)g,
        reinterpret_cast<__attribute__((address_space(3))) unsigned int*>(
            reinterpret_cast<uintptr_t>(l)),
        16, 0, 0);
}

__global__ __launch_bounds__(256, 2) void conv_kernel(
    const signed char* __restrict__ qxp2, const signed char* __restrict__ qwT2,
    const float* __restrict__ sw, const float* __restrict__ bias,
    const float* __restrict__ sx, float* __restrict__ out)
{
    // buf b (b=0,1): A at b*32768 ([kc][row][16]), B at b*32768+16384
    // epilogue aliases: lt[64][132]f (33792 B) + invS(512 B) + biasS(512 B)
    __shared__ __align__(16) signed char smem[65536];

    const int tid  = threadIdx.x;
    const int wave = tid >> 6;
    const int lane = tid & 63;
    const int quad = lane >> 4;
    const int l15  = lane & 15;

    // XCD-bijective swizzle (1568 = 8*196): each XCD gets a contiguous swz
    // range; the two o-tiles of one spatial tile are adjacent -> B-tile L2 reuse.
    const int bid = blockIdx.x;
    const int swz = (bid & 7) * 196 + (bid >> 3);
    const int s0  = (swz >> 1) * 128;   // spatial tile
    const int o0  = (swz & 1) * 128;    // out-channel tile

    // per-lane pixel indices (padded space) for B rows {lane, lane+64}
    const unsigned sp0 = (unsigned)(s0 + lane);
    const unsigned sp1 = (unsigned)(s0 + 64 + lane);
    unsigned b0 = sp0 / HW_, r0 = sp0 - b0*HW_;
    unsigned b1 = sp1 / HW_, r1 = sp1 - b1*HW_;
    unsigned h0 = r0 / 56,   w0 = r0 - h0*56;
    unsigned h1 = r1 / 56,   w1 = r1 - h1*56;
    const size_t bOff0 = ((size_t)(b0*HP_ + h0)*WP_ + w0)*16;   // + kshift per step
    const size_t bOff1 = ((size_t)(b1*HP_ + h1)*WP_ + w1)*16;
    const size_t aOff0 = (size_t)(o0 + lane)*16;                // rows 0..63
    const size_t aOff1 = aOff0 + 1024;                          // rows 64..127

    int32x4 acc[4][4];
    #pragma unroll
    for (int i = 0; i < 4; ++i)
        #pragma unroll
        for (int j = 0; j < 4; ++j)
            acc[i][j] = (int32x4){0,0,0,0};

    const int wo = (wave & 1) << 6;          // o half of wave tile
    const int wn = (wave >> 1) << 6;         // spatial half

    // stage K-step st (st = kk*2 + hf) into (bufA, bufB): 8 global_load_lds/wave
    auto stage = [&](int st, signed char* bufA, signed char* bufB) {
        const int kk  = st >> 1;
        const int cq0 = (st & 1) * 8;
        const size_t kshift = (size_t)((kk/3)*WP_ + (kk%3))*16;   // pixel shift bytes
        const size_t aKK = (size_t)kk*16*4096;
        #pragma unroll
        for (int t = 0; t < 2; ++t) {
            const int kc = 2*wave + t;          // this wave's LDS chunks
            const int cq = cq0 + kc;
            const signed char* aG = qwT2 + aKK + (size_t)cq*4096;
            load16_lds(aG + aOff0, bufA + kc*2048);
            load16_lds(aG + aOff1, bufA + kc*2048 + 1024);
            const signed char* bG = qxp2 + (size_t)cq*PLANE_B + kshift;
            load16_lds(bG + bOff0, bufB + kc*2048);
            load16_lds(bG + bOff1, bufB + kc*2048 + 1024);
        }
    };

    stage(0, smem, smem + 16384);            // prologue: 8 loads in flight

    for (int st = 0; st < 18; ++st) {
        signed char* ldsA = smem + ((st & 1) << 15);
        signed char* ldsB = ldsA + 16384;
        if (st < 17) {
            signed char* nb = smem + (((st + 1) & 1) << 15);
            stage(st + 1, nb, nb + 16384);   // 8 more in flight (16 total)
            asm volatile("s_waitcnt vmcnt(8)");   // my step-st loads done; next 8 fly on
        } else {
            asm volatile("s_waitcnt vmcnt(0)");
        }
        __builtin_amdgcn_s_barrier();        // all waves' step-st stores visible
        __builtin_amdgcn_sched_barrier(0);   // fence: no ds_read hoists above (rule #18)
        #pragma unroll
        for (int ks = 0; ks < 2; ++ks) {
            const int ck = (ks*4 + quad)*2048;
            int32x4 af[4], bf[4];
            #pragma unroll
            for (int t = 0; t < 4; ++t) {
                af[t] = *(const int32x4*)&ldsA[ck + (wo + t*16 + l15)*16];
                bf[t] = *(const int32x4*)&ldsB[ck + (wn + t*16 + l15)*16];
            }
            __builtin_amdgcn_s_setprio(1);
            #pragma unroll
            for (int mt = 0; mt < 4; ++mt)
                #pragma unroll
                for (int nt = 0; nt < 4; ++nt)
                    acc[mt][nt] = __builtin_amdgcn_mfma_i32_16x16x64_i8(
                        af[mt], bf[nt], acc[mt][nt], 0, 0, 0);
            __builtin_amdgcn_s_setprio(0);
        }
        __builtin_amdgcn_sched_barrier(0);   // fence: nothing sinks past read-done barrier
        __builtin_amdgcn_s_barrier();        // all waves done reading buf[st&1]
    }
    asm volatile("" ::: "memory");           // keep epilogue VMEM out of the counted loop

    // ---- epilogue: LDS transpose -> full-line float4 stores ----
    // pass p covers o_local in [p*64, p*64+64); written by waves with wo == p*64
    float* lt    = (float*)smem;                   // [64][132] floats = 33792 B
    float* invS  = (float*)(smem + 33792);
    float* biasS = (float*)(smem + 34304);
    if (tid < 128) {
        float s = sw[o0 + tid];
        invS[tid]  = 1.0f / (s * sx[0]);
        biasS[tid] = bias[o0 + tid];
    }
    #pragma unroll
    for (int p = 0; p < 2; ++p) {
        __syncthreads();
        if ((wave & 1) == p) {
            #pragma unroll
            for (int mt = 0; mt < 4; ++mt)
                #pragma unroll
                for (int nt = 0; nt < 4; ++nt)
                    #pragma unroll
                    for (int r = 0; r < 4; ++r)
                        lt[(mt*16 + quad*4 + r)*132 + wn + nt*16 + l15]
                            = (float)acc[mt][nt][r];
        }
        __syncthreads();
        #pragma unroll
        for (int i = 0; i < 8; ++i) {
            int idx = i*256 + tid;                 // 2048 float4 chunks
            int o = idx >> 5;                      // 0..63
            int c = idx & 31;                      // sp/4 chunk
            float4 v = *(const float4*)&lt[o*132 + 4*c];
            int ol = p*64 + o;
            float is = invS[ol], bs = biasS[ol];
            unsigned sp = (unsigned)(s0 + 4*c);
            unsigned b  = sp / HW_;
            unsigned pos = sp - b*HW_;
            float4 wv;
            wv.x = fmaf(v.x, is, bs); wv.y = fmaf(v.y, is, bs);
            wv.z = fmaf(v.z, is, bs); wv.w = fmaf(v.w, is, bs);
            *(float4*)(out + (size_t)b*CHW_ + (size_t)(o0 + ol)*HW_ + pos) = wv;
        }
    }
}

extern "C" void kernel_launch(void* const* d_in, const int* in_sizes, int n_in,
                              void* d_out, int out_size, void* d_ws, size_t ws_size,
                              hipStream_t stream)
{
    (void)in_sizes; (void)n_in; (void)out_size; (void)ws_size;
    const float* x    = (const float*)d_in[0];
    const float* wgt  = (const float*)d_in[1];
    const float* bias = (const float*)d_in[2];
    const float* sw   = (const float*)d_in[3];
    const float* sx   = (const float*)d_in[4];
    float* out = (float*)d_out;

    signed char* qxp2 = (signed char*)d_ws;           // [cq][b][hp][wp][16]
    signed char* qwT2 = qxp2 + QXP_BYTES;             // [kk][cq][o][16]

    halo_rows_kernel<<<232, 256, 0, stream>>>(qxp2);
    quant_w_kernel<<<256, 256, 0, stream>>>(wgt, sw, qwT2);
    quant_x_kernel<<<1792, 256, 0, stream>>>(x, sx, qxp2);
    conv_kernel<<<1568, 256, 0, stream>>>(qxp2, qwT2, sw, bias, sx, out);
}

// Round 2
// 267.010 us; speedup vs baseline: 1.0634x; 1.0156x over previous
//
#include <hip/hip_runtime.h>
#include <stdint.h>

typedef int int32x4 __attribute__((ext_vector_type(4)));

#define HW_        3136          // 56*56
#define CHW_       802816        // 256*3136
#define HP_        58
#define WP_        58
#define PLANE_PIX  107648ull     // 32*58*58 pixels per 16-channel plane
#define PLANE_B    (PLANE_PIX*16)        // 1,722,368 B
#define QXP_BYTES  (16ull*PLANE_B)       // 27,557,888 B : [cq][b][hp][wp][16]
#define QWT_BYTES  (9ull*16*256*16)      // 589,824  B : [kk][cq][o][16]

__device__ __forceinline__ signed char quant8(float v, float s) {
    float t = v * s;
    t = fmaxf(t, -128.0f);                 // clip FIRST (round(clip(...)))
    t = fminf(t, 127.0f);
    return (signed char)(int)rintf(t);     // half-to-even == jnp.round
}

// ---------------- halo rows: zero padded rows hp=0 and hp=57 (all b, cq) ----------------
__global__ __launch_bounds__(256) void halo_rows_kernel(signed char* __restrict__ qxp2) {
    int idx = blockIdx.x*256 + threadIdx.x;     // 16*32*2*58 = 59392 chunks
    if (idx < 16*32*2*58) {
        int cq = idx / (32*2*58);
        int r  = idx % (32*2*58);
        int b  = r / (2*58);
        int t  = r % (2*58);
        int hp = (t / 58) * (HP_-1);
        int wp = t % 58;
        *(int32x4*)(qxp2 + ((size_t)cq*PLANE_PIX + (size_t)(b*HP_+hp)*WP_ + wp)*16)
            = (int32x4){0,0,0,0};
    }
}

// ---------------- weight quantize: w[o][c][3][3] -> qwT2[kk][cq][o][16] ----------------
__global__ __launch_bounds__(256) void quant_w_kernel(
    const float* __restrict__ wgt, const float* __restrict__ sw,
    signed char* __restrict__ qwT2)
{
    __shared__ __align__(16) signed char lw[9*272];
    const int o = blockIdx.x, c = threadIdx.x;
    const float s = sw[o];
    const float* wp = wgt + ((size_t)o*256 + c)*9;
    #pragma unroll
    for (int kk = 0; kk < 9; ++kk)
        lw[kk*272 + c] = quant8(wp[kk], s);
    __syncthreads();
    if (c < 144) {
        int kk = c / 16, cq = c - kk*16;
        int32x4 v = *(const int32x4*)&lw[kk*272 + cq*16];
        *(int32x4*)(qwT2 + ((size_t)(kk*16 + cq)*256 + o)*16) = v;
    }
}

// ---------------- activation quantize: x NCHW fp32 -> qxp2[cq][b][hp][wp][16] ----------------
__global__ __launch_bounds__(256) void quant_x_kernel(
    const float* __restrict__ x, const float* __restrict__ sx,
    signed char* __restrict__ qxp2)
{
    const int tid = threadIdx.x;
    const int bh = blockIdx.x;                // 32*56
    const int b = bh / 56, h = bh % 56;
    const float s = sx[0];
    if (tid < 224) {
        const int w  = tid % 56;
        const int cg = tid / 56;              // 0..3 -> cq = cg*4+k
        const size_t xrow = (size_t)b*CHW_ + (size_t)h*56 + w;
        const size_t pb = ((size_t)(b*HP_ + h + 1)*WP_ + 1 + w)*16;
        #pragma unroll
        for (int k = 0; k < 4; ++k) {
            const int cq = cg*4 + k;
            const float* xp = x + xrow + (size_t)(cq*16)*HW_;
            int pk[4];
            #pragma unroll
            for (int g = 0; g < 4; ++g) {
                int b0 = (unsigned char)quant8(xp[(size_t)(4*g+0)*HW_], s);
                int b1 = (unsigned char)quant8(xp[(size_t)(4*g+1)*HW_], s);
                int b2 = (unsigned char)quant8(xp[(size_t)(4*g+2)*HW_], s);
                int b3 = (unsigned char)quant8(xp[(size_t)(4*g+3)*HW_], s);
                pk[g] = b0 | (b1 << 8) | (b2 << 16) | (b3 << 24);
            }
            *(int32x4*)(qxp2 + (size_t)cq*PLANE_B + pb) = (int32x4){pk[0],pk[1],pk[2],pk[3]};
        }
    } else {
        // w-halo of this padded row: w = 0 and 57, all 16 cq
        int t2 = tid - 224;                   // 0..31
        int cq = t2 >> 1, wp = (t2 & 1) * (WP_-1);
        const size_t rowpix = (size_t)(b*HP_ + h + 1)*WP_;
        *(int32x4*)(qxp2 + ((size_t)cq*PLANE_PIX + rowpix + wp)*16) = (int32x4){0,0,0,0};
    }
}

// ---------------- int8 implicit-GEMM conv ----------------
// A = qwT2 (M=o) read DIRECTLY from global (L1/L2-resident, fragment-layout match),
// register-prefetched one K-step ahead. B = qxp2 staged through a 2x16KB LDS
// double buffer via global_load_lds with counted vmcnt(12). This halves LDS
// pipe traffic vs A+B staging (the round-1 bottleneck: LDS BW saturated).
__device__ __forceinline__ void load16_lds(const void* g, void* l) {
    __builtin_amdgcn_global_load_lds(
        (const unsigned int*)g,
        reinterpret_cast<__attribute__((address_space(3))) unsigned int*>(
            reinterpret_cast<uintptr_t>(l)),
        16, 0, 0);
}

// A-fragment loads for K-step st into register array AF[8] (AF[ks*4+t]).
// chunk = cq0 + ks*4 + quad (quad folded into aRowQ), row = o0+wo+t*16+l15.
#define LOADA(st, AF) {                                                        \
    const signed char* aG_ = qwT2 + (size_t)((st) >> 1)*65536                  \
                           + (size_t)(((st) & 1) * 8)*4096 + aRowQ;            \
    AF[0] = *(const int32x4*)(aG_ +     0);                                    \
    AF[1] = *(const int32x4*)(aG_ +   256);                                    \
    AF[2] = *(const int32x4*)(aG_ +   512);                                    \
    AF[3] = *(const int32x4*)(aG_ +   768);                                    \
    AF[4] = *(const int32x4*)(aG_ + 16384);                                    \
    AF[5] = *(const int32x4*)(aG_ + 16640);                                    \
    AF[6] = *(const int32x4*)(aG_ + 16896);                                    \
    AF[7] = *(const int32x4*)(aG_ + 17152);                                    \
}

// One K-step: (optionally) stage next B + prefetch next A, counted wait,
// barrier, 8x ds_read_b128 (B) + 32 MFMA with register A, barrier.
#define STEP(st, AFC, AFN, LAST) {                                             \
    signed char* ldsB_ = smem + (((st) & 1) << 14);                            \
    if (!(LAST)) {                                                             \
        stageB((st) + 1, smem + ((((st) + 1) & 1) << 14));                     \
        LOADA((st) + 1, AFN);                                                  \
        __builtin_amdgcn_sched_barrier(0);                                     \
        asm volatile("s_waitcnt vmcnt(12)");                                   \
    } else {                                                                   \
        asm volatile("s_waitcnt vmcnt(0)");                                    \
    }                                                                          \
    __builtin_amdgcn_s_barrier();                                              \
    __builtin_amdgcn_sched_barrier(0);                                         \
    _Pragma("unroll")                                                          \
    for (int ks = 0; ks < 2; ++ks) {                                           \
        const int ck = (ks*4 + quad)*2048;                                     \
        int32x4 bf[4];                                                         \
        _Pragma("unroll")                                                      \
        for (int t = 0; t < 4; ++t)                                            \
            bf[t] = *(const int32x4*)&ldsB_[ck + (wn + t*16 + l15)*16];        \
        __builtin_amdgcn_s_setprio(1);                                         \
        _Pragma("unroll")                                                      \
        for (int mt = 0; mt < 4; ++mt)                                         \
            _Pragma("unroll")                                                  \
            for (int nt = 0; nt < 4; ++nt)                                     \
                acc[mt][nt] = __builtin_amdgcn_mfma_i32_16x16x64_i8(           \
                    AFC[ks*4 + mt], bf[nt], acc[mt][nt], 0, 0, 0);             \
        __builtin_amdgcn_s_setprio(0);                                         \
    }                                                                          \
    __builtin_amdgcn_sched_barrier(0);                                         \
    __builtin_amdgcn_s_barrier();                                              \
}

__global__ __launch_bounds__(256, 2) void conv_kernel(
    const signed char* __restrict__ qxp2, const signed char* __restrict__ qwT2,
    const float* __restrict__ sw, const float* __restrict__ bias,
    const float* __restrict__ sx, float* __restrict__ out)
{
    // K-loop: B double buffer 2x16KB at [0,32768).
    // epilogue aliases: lt[64][132]f (33792 B) + invS(512 B) + biasS(512 B)
    __shared__ __align__(16) signed char smem[34816];

    const int tid  = threadIdx.x;
    const int wave = tid >> 6;
    const int lane = tid & 63;
    const int quad = lane >> 4;
    const int l15  = lane & 15;

    // XCD-bijective swizzle (1568 = 8*196); o-tile pair adjacent -> L2 reuse.
    const int bid = blockIdx.x;
    const int swz = (bid & 7) * 196 + (bid >> 3);
    const int s0  = (swz >> 1) * 128;   // spatial tile
    const int o0  = (swz & 1) * 128;    // out-channel tile

    // per-lane pixel indices (padded space) for B rows {lane, lane+64}
    const unsigned sp0 = (unsigned)(s0 + lane);
    const unsigned sp1 = (unsigned)(s0 + 64 + lane);
    unsigned b0 = sp0 / HW_, r0 = sp0 - b0*HW_;
    unsigned b1 = sp1 / HW_, r1 = sp1 - b1*HW_;
    unsigned h0 = r0 / 56,   w0 = r0 - h0*56;
    unsigned h1 = r1 / 56,   w1 = r1 - h1*56;
    const size_t bOff0 = ((size_t)(b0*HP_ + h0)*WP_ + w0)*16;   // + kshift per step
    const size_t bOff1 = ((size_t)(b1*HP_ + h1)*WP_ + w1)*16;

    const int wo = (wave & 1) << 6;          // o half of wave tile
    const int wn = (wave >> 1) << 6;         // spatial half
    const size_t aRowQ = (size_t)quad*4096 + (size_t)(o0 + wo + l15)*16;

    int32x4 acc[4][4];
    #pragma unroll
    for (int i = 0; i < 4; ++i)
        #pragma unroll
        for (int j = 0; j < 4; ++j)
            acc[i][j] = (int32x4){0,0,0,0};

    // stage B for K-step st: 4 global_load_lds/wave (chunks kc=2w..2w+1)
    auto stageB = [&](int st, signed char* bufB) {
        const int kk  = st >> 1;
        const int cq0 = (st & 1) * 8;
        const size_t kshift = (size_t)((kk/3)*WP_ + (kk%3))*16;   // pixel shift bytes
        #pragma unroll
        for (int t = 0; t < 2; ++t) {
            const int kc = 2*wave + t;
            const signed char* bG = qxp2 + (size_t)(cq0 + kc)*PLANE_B + kshift;
            load16_lds(bG + bOff0, bufB + kc*2048);
            load16_lds(bG + bOff1, bufB + kc*2048 + 1024);
        }
    };

    int32x4 aP[8], aQ[8];
    stageB(0, smem);                         // prologue: 4 B-loads in flight
    LOADA(0, aP);                            // + 8 A-loads

    #pragma unroll 1
    for (int s2 = 0; s2 < 8; ++s2) {         // st = 0..15
        const int st0 = 2*s2;
        STEP(st0,     aP, aQ, false);
        STEP(st0 + 1, aQ, aP, false);
    }
    STEP(16, aP, aQ, false);
    STEP(17, aQ, aP, true);

    asm volatile("" ::: "memory");           // keep epilogue VMEM out of the counted loop

    // ---- epilogue: LDS transpose -> full-line float4 stores ----
    float* lt    = (float*)smem;                   // [64][132] floats = 33792 B
    float* invS  = (float*)(smem + 33792);
    float* biasS = (float*)(smem + 34304);
    if (tid < 128) {
        float s = sw[o0 + tid];
        invS[tid]  = 1.0f / (s * sx[0]);
        biasS[tid] = bias[o0 + tid];
    }
    #pragma unroll
    for (int p = 0; p < 2; ++p) {
        __syncthreads();
        if ((wave & 1) == p) {
            #pragma unroll
            for (int mt = 0; mt < 4; ++mt)
                #pragma unroll
                for (int nt = 0; nt < 4; ++nt)
                    #pragma unroll
                    for (int r = 0; r < 4; ++r)
                        lt[(mt*16 + quad*4 + r)*132 + wn + nt*16 + l15]
                            = (float)acc[mt][nt][r];
        }
        __syncthreads();
        #pragma unroll
        for (int i = 0; i < 8; ++i) {
            int idx = i*256 + tid;                 // 2048 float4 chunks
            int o = idx >> 5;                      // 0..63
            int c = idx & 31;                      // sp/4 chunk
            float4 v = *(const float4*)&lt[o*132 + 4*c];
            int ol = p*64 + o;
            float is = invS[ol], bs = biasS[ol];
            unsigned sp = (unsigned)(s0 + 4*c);
            unsigned b  = sp / HW_;
            unsigned pos = sp - b*HW_;
            float4 wv;
            wv.x = fmaf(v.x, is, bs); wv.y = fmaf(v.y, is, bs);
            wv.z = fmaf(v.z, is, bs); wv.w = fmaf(v.w, is, bs);
            *(float4*)(out + (size_t)b*CHW_ + (size_t)(o0 + ol)*HW_ + pos) = wv;
        }
    }
}

extern "C" void kernel_launch(void* const* d_in, const int* in_sizes, int n_in,
                              void* d_out, int out_size, void* d_ws, size_t ws_size,
                              hipStream_t stream)
{
    (void)in_sizes; (void)n_in; (void)out_size; (void)ws_size;
    const float* x    = (const float*)d_in[0];
    const float* wgt  = (const float*)d_in[1];
    const float* bias = (const float*)d_in[2];
    const float* sw   = (const float*)d_in[3];
    const float* sx   = (const float*)d_in[4];
    float* out = (float*)d_out;

    signed char* qxp2 = (signed char*)d_ws;           // [cq][b][hp][wp][16]
    signed char* qwT2 = qxp2 + QXP_BYTES;             // [kk][cq][o][16]

    halo_rows_kernel<<<232, 256, 0, stream>>>(qxp2);
    quant_w_kernel<<<256, 256, 0, stream>>>(wgt, sw, qwT2);
    quant_x_kernel<<<1792, 256, 0, stream>>>(x, sx, qxp2);
    conv_kernel<<<1568, 256, 0, stream>>>(qxp2, qwT2, sw, bias, sx, out);
}

// Round 3
// 263.868 us; speedup vs baseline: 1.0761x; 1.0119x over previous
//
#include <hip/hip_runtime.h>
#include <stdint.h>

typedef int int32x4 __attribute__((ext_vector_type(4)));

#define HW_        3136          // 56*56
#define CHW_       802816        // 256*3136
#define HP_        58
#define WP_        58
#define PLANE_PIX  107648ull     // 32*58*58 pixels per 16-channel plane
#define PLANE_B    (PLANE_PIX*16)        // 1,722,368 B
#define QXP_BYTES  (16ull*PLANE_B)       // 27,557,888 B : [cq][b][hp][wp][16]
#define QWT_BYTES  (9ull*16*256*16)      // 589,824  B : [kk][cq][o][16]

__device__ __forceinline__ signed char quant8(float v, float s) {
    float t = v * s;
    t = fmaxf(t, -128.0f);                 // clip FIRST (round(clip(...)))
    t = fminf(t, 127.0f);
    return (signed char)(int)rintf(t);     // half-to-even == jnp.round
}

// ---------------- fused prep: quant_x + row-halo (+ quant_w on blocks >=1792) ----------------
__global__ __launch_bounds__(256) void prep_kernel(
    const float* __restrict__ x, const float* __restrict__ sx,
    const float* __restrict__ wgt, const float* __restrict__ sw,
    signed char* __restrict__ qxp2, signed char* __restrict__ qwT2)
{
    __shared__ __align__(16) signed char lw[9*272];
    const int tid = threadIdx.x;
    const int blk = blockIdx.x;

    if (blk >= 1792) {                     // ---- quant_w: o = blk-1792 ----
        const int o = blk - 1792;
        const float s = sw[o];
        const float* wp = wgt + ((size_t)o*256 + tid)*9;
        #pragma unroll
        for (int kk = 0; kk < 9; ++kk)
            lw[kk*272 + tid] = quant8(wp[kk], s);
        __syncthreads();
        if (tid < 144) {
            int kk = tid / 16, cq = tid - kk*16;
            int32x4 v = *(const int32x4*)&lw[kk*272 + cq*16];
            *(int32x4*)(qwT2 + ((size_t)(kk*16 + cq)*256 + o)*16) = v;
        }
        return;
    }

    // ---- quant_x for (b,h) = blk ----
    const int b = blk / 56, h = blk % 56;
    const float s = sx[0];
    if (tid < 224) {
        const int w  = tid % 56;
        const int cg = tid / 56;              // 0..3 -> cq = cg*4+k
        const size_t xrow = (size_t)b*CHW_ + (size_t)h*56 + w;
        const size_t pb = ((size_t)(b*HP_ + h + 1)*WP_ + 1 + w)*16;
        #pragma unroll
        for (int k = 0; k < 4; ++k) {
            const int cq = cg*4 + k;
            const float* xp = x + xrow + (size_t)(cq*16)*HW_;
            int pk[4];
            #pragma unroll
            for (int g = 0; g < 4; ++g) {
                int b0 = (unsigned char)quant8(xp[(size_t)(4*g+0)*HW_], s);
                int b1 = (unsigned char)quant8(xp[(size_t)(4*g+1)*HW_], s);
                int b2 = (unsigned char)quant8(xp[(size_t)(4*g+2)*HW_], s);
                int b3 = (unsigned char)quant8(xp[(size_t)(4*g+3)*HW_], s);
                pk[g] = b0 | (b1 << 8) | (b2 << 16) | (b3 << 24);
            }
            *(int32x4*)(qxp2 + (size_t)cq*PLANE_B + pb) = (int32x4){pk[0],pk[1],pk[2],pk[3]};
        }
    } else {
        // w-halo of this padded row: w = 0 and 57, all 16 cq
        int t2 = tid - 224;                   // 0..31
        int cq = t2 >> 1, wp = (t2 & 1) * (WP_-1);
        const size_t rowpix = (size_t)(b*HP_ + h + 1)*WP_;
        *(int32x4*)(qxp2 + ((size_t)cq*PLANE_PIX + rowpix + wp)*16) = (int32x4){0,0,0,0};
    }
    if (h == 0) {
        // row-halo: zero padded rows hp=0 and hp=57 for this b (all cq)
        for (int t = tid; t < 16*2*58; t += 256) {
            int cq = t / 116;
            int r  = t - cq*116;
            int hp = (r / 58) * (HP_-1);
            int wp = r % 58;
            *(int32x4*)(qxp2 + ((size_t)cq*PLANE_PIX + (size_t)(b*HP_+hp)*WP_ + wp)*16)
                = (int32x4){0,0,0,0};
        }
    }
}

// ---------------- int8 implicit-GEMM conv ----------------
// BK=64 (36 K-steps), fully unrolled. B triple-buffered in LDS (3 x 8KB),
// staged TWO steps ahead via global_load_lds; A (weights) direct global->reg,
// one step ahead. ONE s_barrier per step; counted vmcnt(6) never drains the
// pipeline. All offsets / immediates compile-time constants.
__device__ __forceinline__ void load16_lds(const void* g, void* l) {
    __builtin_amdgcn_global_load_lds(
        (const unsigned int*)g,
        reinterpret_cast<__attribute__((address_space(3))) unsigned int*>(
            reinterpret_cast<uintptr_t>(l)),
        16, 0, 0);
}

// A-fragment loads for K-step st (4 x int32x4): chunk cq=(st&3)*4+quad,
// rows o0+wo+t*16+l15 (quad and row folded into aRow).
#define LOADA4(st, AF) {                                                      \
    const signed char* aG_ = qwT2 + (size_t)(((st) >> 2)*65536                \
                           + (((st) & 3)*4)*4096) + aRow;                     \
    AF[0] = *(const int32x4*)(aG_ +   0);                                     \
    AF[1] = *(const int32x4*)(aG_ + 256);                                     \
    AF[2] = *(const int32x4*)(aG_ + 512);                                     \
    AF[3] = *(const int32x4*)(aG_ + 768);                                     \
}

// stage B for K-step st into buf[(st)%3]: 2 x global_load_lds per wave
// (wave wv stages chunk wv, pixel-rows {0..63, 64..127}).
#define STAGEB(st) {                                                          \
    const size_t ksh_ = (size_t)((((st) >> 2)/3)*WP_ + (((st) >> 2)%3))*16;   \
    const signed char* bG_ = qxp2 + (size_t)(((st) & 3)*4)*PLANE_B            \
                           + wOffB + ksh_;                                    \
    signed char* dst_ = smem + ((st)%3)*8192 + dstW;                          \
    load16_lds(bG_ + bOff0, dst_);                                            \
    load16_lds(bG_ + bOff1, dst_ + 1024);                                     \
}

// One K-step. Region layout: [wait][barrier][SB0] loads+reads+MFMA [SB0].
// vmcnt(6): leaves A(st),B(st+1) (6 loads) in flight -> pipeline never drains.
#define STEP(st, AC, AN) {                                                    \
    if ((st) == 35) asm volatile("s_waitcnt vmcnt(4)");                       \
    else            asm volatile("s_waitcnt vmcnt(6)");                       \
    __builtin_amdgcn_s_barrier();                                             \
    __builtin_amdgcn_sched_barrier(0);                                        \
    if ((st) + 1 < 36) LOADA4((st) + 1, AN);                                  \
    if ((st) + 2 < 36) STAGEB((st) + 2);                                      \
    const signed char* bR_ = smem + ((st)%3)*8192;                            \
    int32x4 bf[4];                                                            \
    _Pragma("unroll")                                                         \
    for (int t = 0; t < 4; ++t)                                               \
        bf[t] = *(const int32x4*)&bR_[rdOff + t*256];                         \
    __builtin_amdgcn_s_setprio(1);                                            \
    _Pragma("unroll")                                                         \
    for (int mt = 0; mt < 4; ++mt)                                            \
        _Pragma("unroll")                                                     \
        for (int nt = 0; nt < 4; ++nt)                                        \
            acc[mt][nt] = __builtin_amdgcn_mfma_i32_16x16x64_i8(              \
                AC[mt], bf[nt], acc[mt][nt], 0, 0, 0);                        \
    __builtin_amdgcn_s_setprio(0);                                            \
    __builtin_amdgcn_sched_barrier(0);                                        \
}

#define STEP2(s) STEP((s),   aP, aQ) STEP((s)+1, aQ, aP)
#define STEP6(s) STEP2(s) STEP2((s)+2) STEP2((s)+4)

__global__ __launch_bounds__(256, 3) void conv_kernel(
    const signed char* __restrict__ qxp2, const signed char* __restrict__ qwT2,
    const float* __restrict__ sw, const float* __restrict__ bias,
    const float* __restrict__ sx, float* __restrict__ out)
{
    // K-loop: B triple buffer 3x8KB at [0,24576).
    // epilogue aliases: lt[64][132]f (33792 B) + invS(512 B) + biasS(512 B)
    __shared__ __align__(16) signed char smem[34816];

    const int tid  = threadIdx.x;
    const int wv   = tid >> 6;
    const int lane = tid & 63;
    const int quad = lane >> 4;
    const int l15  = lane & 15;

    // XCD-bijective swizzle (1568 = 8*196); o-tile pair adjacent -> L2 reuse.
    const int bid = blockIdx.x;
    const int swz = (bid & 7) * 196 + (bid >> 3);
    const int s0  = (swz >> 1) * 128;   // spatial tile
    const int o0  = (swz & 1) * 128;    // out-channel tile

    // per-lane pixel indices (padded space) for B rows {lane, lane+64}
    const unsigned sp0 = (unsigned)(s0 + lane);
    const unsigned sp1 = (unsigned)(s0 + 64 + lane);
    unsigned b0 = sp0 / HW_, r0 = sp0 - b0*HW_;
    unsigned b1 = sp1 / HW_, r1 = sp1 - b1*HW_;
    unsigned h0 = r0 / 56,   w0 = r0 - h0*56;
    unsigned h1 = r1 / 56,   w1 = r1 - h1*56;
    const size_t bOff0 = ((size_t)(b0*HP_ + h0)*WP_ + w0)*16;   // + kshift per step
    const size_t bOff1 = ((size_t)(b1*HP_ + h1)*WP_ + w1)*16;

    const int wo = (wv & 1) << 6;            // o half of wave tile
    const int wn = (wv >> 1) << 6;           // spatial half
    const size_t aRow  = (size_t)quad*4096 + (size_t)(o0 + wo + l15)*16;
    const size_t wOffB = (size_t)wv*PLANE_B; // wave stages chunk wv
    const int    dstW  = wv*2048;
    const int    rdOff = quad*2048 + (wn + l15)*16;

    int32x4 acc[4][4];
    #pragma unroll
    for (int i = 0; i < 4; ++i)
        #pragma unroll
        for (int j = 0; j < 4; ++j)
            acc[i][j] = (int32x4){0,0,0,0};

    int32x4 aP[4], aQ[4];

    // prologue: B(0), B(1) staged, then A(0). Order pinned so vmcnt(6) at
    // step 0 (leaves B(1)+A(0) = 6 in flight) guarantees B(0) landed.
    STAGEB(0);
    STAGEB(1);
    __builtin_amdgcn_sched_barrier(0);
    LOADA4(0, aP);
    __builtin_amdgcn_sched_barrier(0);

    STEP6(0) STEP6(6) STEP6(12) STEP6(18) STEP6(24) STEP6(30)

    asm volatile("" ::: "memory");           // keep epilogue out of the K-loop regions

    // ---- epilogue: LDS transpose -> full-line float4 stores ----
    float* lt    = (float*)smem;                   // [64][132] floats = 33792 B
    float* invS  = (float*)(smem + 33792);
    float* biasS = (float*)(smem + 34304);
    if (tid < 128) {
        float s = sw[o0 + tid];
        invS[tid]  = 1.0f / (s * sx[0]);
        biasS[tid] = bias[o0 + tid];
    }
    #pragma unroll
    for (int p = 0; p < 2; ++p) {
        __syncthreads();
        if ((wv & 1) == p) {
            #pragma unroll
            for (int mt = 0; mt < 4; ++mt)
                #pragma unroll
                for (int nt = 0; nt < 4; ++nt)
                    #pragma unroll
                    for (int r = 0; r < 4; ++r)
                        lt[(mt*16 + quad*4 + r)*132 + wn + nt*16 + l15]
                            = (float)acc[mt][nt][r];
        }
        __syncthreads();
        #pragma unroll
        for (int i = 0; i < 8; ++i) {
            int idx = i*256 + tid;                 // 2048 float4 chunks
            int o = idx >> 5;                      // 0..63
            int c = idx & 31;                      // sp/4 chunk
            float4 v = *(const float4*)&lt[o*132 + 4*c];
            int ol = p*64 + o;
            float is = invS[ol], bs = biasS[ol];
            unsigned sp = (unsigned)(s0 + 4*c);
            unsigned b  = sp / HW_;
            unsigned pos = sp - b*HW_;
            float4 wv4;
            wv4.x = fmaf(v.x, is, bs); wv4.y = fmaf(v.y, is, bs);
            wv4.z = fmaf(v.z, is, bs); wv4.w = fmaf(v.w, is, bs);
            *(float4*)(out + (size_t)b*CHW_ + (size_t)(o0 + ol)*HW_ + pos) = wv4;
        }
    }
}

extern "C" void kernel_launch(void* const* d_in, const int* in_sizes, int n_in,
                              void* d_out, int out_size, void* d_ws, size_t ws_size,
                              hipStream_t stream)
{
    (void)in_sizes; (void)n_in; (void)out_size; (void)ws_size;
    const float* x    = (const float*)d_in[0];
    const float* wgt  = (const float*)d_in[1];
    const float* bias = (const float*)d_in[2];
    const float* sw   = (const float*)d_in[3];
    const float* sx   = (const float*)d_in[4];
    float* out = (float*)d_out;

    signed char* qxp2 = (signed char*)d_ws;           // [cq][b][hp][wp][16]
    signed char* qwT2 = qxp2 + QXP_BYTES;             // [kk][cq][o][16]

    prep_kernel<<<2048, 256, 0, stream>>>(x, sx, wgt, sw, qxp2, qwT2);
    conv_kernel<<<1568, 256, 0, stream>>>(qxp2, qwT2, sw, bias, sx, out);
}

// Round 5
// 249.882 us; speedup vs baseline: 1.1363x; 1.0560x over previous
//
#include <hip/hip_runtime.h>
#include <stdint.h>

typedef int int32x4 __attribute__((ext_vector_type(4)));

#define HW_        3136          // 56*56
#define CHW_       802816        // 256*3136
#define HP_        58
#define WP_        58
#define PLANE_PIX  107648ull     // 32*58*58 pixels per 16-channel plane
#define PLANE_B    (PLANE_PIX*16)        // 1,722,368 B
#define QXP_BYTES  (16ull*PLANE_B)       // 27,557,888 B : [cq][b][hp][wp][16]
#define QWT_BYTES  (9ull*16*256*16)      // 589,824  B : [kk][cq][o][16]

__device__ __forceinline__ signed char quant8(float v, float s) {
    float t = v * s;
    t = fmaxf(t, -128.0f);                 // clip FIRST (round(clip(...)))
    t = fminf(t, 127.0f);
    return (signed char)(int)rintf(t);     // half-to-even == jnp.round
}

// ---------------- fused prep: quant_x + row-halo (+ quant_w on blocks >=1792) ----------------
__global__ __launch_bounds__(256) void prep_kernel(
    const float* __restrict__ x, const float* __restrict__ sx,
    const float* __restrict__ wgt, const float* __restrict__ sw,
    signed char* __restrict__ qxp2, signed char* __restrict__ qwT2)
{
    __shared__ __align__(16) signed char lw[9*272];
    const int tid = threadIdx.x;
    const int blk = blockIdx.x;

    if (blk >= 1792) {                     // ---- quant_w: o = blk-1792 ----
        const int o = blk - 1792;
        const float s = sw[o];
        const float* wp = wgt + ((size_t)o*256 + tid)*9;
        #pragma unroll
        for (int kk = 0; kk < 9; ++kk)
            lw[kk*272 + tid] = quant8(wp[kk], s);
        __syncthreads();
        if (tid < 144) {
            int kk = tid / 16, cq = tid - kk*16;
            int32x4 v = *(const int32x4*)&lw[kk*272 + cq*16];
            *(int32x4*)(qwT2 + ((size_t)(kk*16 + cq)*256 + o)*16) = v;
        }
        return;
    }

    // ---- quant_x for (b,h) = blk ----
    const int b = blk / 56, h = blk % 56;
    const float s = sx[0];
    if (tid < 224) {
        const int w  = tid % 56;
        const int cg = tid / 56;              // 0..3 -> cq = cg*4+k
        const size_t xrow = (size_t)b*CHW_ + (size_t)h*56 + w;
        const size_t pb = ((size_t)(b*HP_ + h + 1)*WP_ + 1 + w)*16;
        #pragma unroll
        for (int k = 0; k < 4; ++k) {
            const int cq = cg*4 + k;
            const float* xp = x + xrow + (size_t)(cq*16)*HW_;
            int pk[4];
            #pragma unroll
            for (int g = 0; g < 4; ++g) {
                int b0 = (unsigned char)quant8(xp[(size_t)(4*g+0)*HW_], s);
                int b1 = (unsigned char)quant8(xp[(size_t)(4*g+1)*HW_], s);
                int b2 = (unsigned char)quant8(xp[(size_t)(4*g+2)*HW_], s);
                int b3 = (unsigned char)quant8(xp[(size_t)(4*g+3)*HW_], s);
                pk[g] = b0 | (b1 << 8) | (b2 << 16) | (b3 << 24);
            }
            *(int32x4*)(qxp2 + (size_t)cq*PLANE_B + pb) = (int32x4){pk[0],pk[1],pk[2],pk[3]};
        }
    } else {
        // w-halo of this padded row: w = 0 and 57, all 16 cq
        int t2 = tid - 224;                   // 0..31
        int cq = t2 >> 1, wp = (t2 & 1) * (WP_-1);
        const size_t rowpix = (size_t)(b*HP_ + h + 1)*WP_;
        *(int32x4*)(qxp2 + ((size_t)cq*PLANE_PIX + rowpix + wp)*16) = (int32x4){0,0,0,0};
    }
    if (h == 0) {
        // row-halo: zero padded rows hp=0 and hp=57 for this b (all cq)
        for (int t = tid; t < 16*2*58; t += 256) {
            int cq = t / 116;
            int r  = t - cq*116;
            int hp = (r / 58) * (HP_-1);
            int wp = r % 58;
            *(int32x4*)(qxp2 + ((size_t)cq*PLANE_PIX + (size_t)(b*HP_+hp)*WP_ + wp)*16)
                = (int32x4){0,0,0,0};
        }
    }
}

// ---------------- int8 implicit-GEMM conv, kw-tap-reuse supersteps ----------------
// 12 supersteps = (kh 0..2) x (cq-group 0..3). Per superstep: stage ONE
// contiguous 256-slot padded span per chunk (covers tile + row/batch gaps +
// kw halo; worst-case need = 251 slots), then 3 kw-taps x 16 MFMA = 48 MFMA
// per barrier. B triple-buffered (3 x 16KB), staged 2 supersteps ahead;
// A direct global->reg, prefetched one tap ahead (ping-pong).
__device__ __forceinline__ void load16_lds(const void* g, void* l) {
    __builtin_amdgcn_global_load_lds(
        (const unsigned int*)g,
        reinterpret_cast<__attribute__((address_space(3))) unsigned int*>(
            reinterpret_cast<uintptr_t>(l)),
        16, 0, 0);
}

// kh = st>>2, g = st&3
// stage chunk wv for superstep st: 4 x 1KB contiguous into buf[st%3].
// LDS dest is WAVE-UNIFORM base (HW adds lane*16); global src is per-lane.
#define STAGEB(st) {                                                          \
    const signed char* bG_ = qxp2                                             \
        + (size_t)(((st) & 3)*4 + wv)*PLANE_B                                 \
        + (base0 + (size_t)((st) >> 2)*WP_)*16 + (size_t)lane*16;             \
    signed char* dst_ = smem + ((st)%3)*16384 + wv*4096;                      \
    load16_lds(bG_ +    0, dst_ +    0);                                      \
    load16_lds(bG_ + 1024, dst_ + 1024);                                      \
    load16_lds(bG_ + 2048, dst_ + 2048);                                      \
    load16_lds(bG_ + 3072, dst_ + 3072);                                      \
}

// A fragment for (superstep nst, tap nkw) -> AF[0..3]
#define LOADA(nst, nkw, AF) {                                                 \
    const signed char* aG_ = aBase + (size_t)((((nst) >> 2)*3 + (nkw))*65536  \
                           + ((nst) & 3)*16384);                              \
    AF[0] = *(const int32x4*)(aG_ +   0);                                     \
    AF[1] = *(const int32x4*)(aG_ + 256);                                     \
    AF[2] = *(const int32x4*)(aG_ + 512);                                     \
    AF[3] = *(const int32x4*)(aG_ + 768);                                     \
}

// one tap: prefetch next A, 4 ds_read (imm offset = buf + kw*16), 16 MFMA
#define TAP(st, kw, AC, AN, nst, nkw) {                                       \
    if ((nst) < 12) LOADA(nst, nkw, AN);                                      \
    int32x4 bf[4];                                                            \
    _Pragma("unroll")                                                         \
    for (int t = 0; t < 4; ++t)                                               \
        bf[t] = *(const int32x4*)&smem[rA[t] + ((st)%3)*16384 + (kw)*16];     \
    __builtin_amdgcn_s_setprio(1);                                            \
    _Pragma("unroll")                                                         \
    for (int mt = 0; mt < 4; ++mt)                                            \
        _Pragma("unroll")                                                     \
        for (int nt = 0; nt < 4; ++nt)                                        \
            acc[mt][nt] = __builtin_amdgcn_mfma_i32_16x16x64_i8(              \
                AC[mt], bf[nt], acc[mt][nt], 0, 0, 0);                        \
    __builtin_amdgcn_s_setprio(0);                                            \
    __builtin_amdgcn_sched_barrier(0);                                        \
}

// superstep: wait B(st) landed (vmcnt(8): leaves stage(st+1)+A(st,0) in
// flight), barrier, stage B(st+2), 3 taps. A ping-pong flips odd (3 taps).
#define SS(st, X, Y) {                                                        \
    asm volatile("s_waitcnt vmcnt(8)");                                       \
    __builtin_amdgcn_s_barrier();                                             \
    __builtin_amdgcn_sched_barrier(0);                                        \
    if ((st) + 2 < 12) STAGEB((st) + 2);                                      \
    TAP(st, 0, X, Y, st, 1)                                                   \
    TAP(st, 1, Y, X, st, 2)                                                   \
    TAP(st, 2, X, Y, (st) + 1, 0)                                             \
}

__global__ __launch_bounds__(256, 3) void conv_kernel(
    const signed char* __restrict__ qxp2, const signed char* __restrict__ qwT2,
    const float* __restrict__ sw, const float* __restrict__ bias,
    const float* __restrict__ sx, float* __restrict__ out)
{
    // B triple buffer: 3 x (4 chunks x 4096 B) = 49152.
    // epilogue aliases (ONLY after the post-K-loop __syncthreads rendezvous —
    // round-4 bug: invS at 33792 is inside buf2, racing SS(11)'s reads):
    // lt[64][132]f (33792 B) + invS/biasS at 33792/34304.
    __shared__ __align__(16) signed char smem[49152];

    const int tid  = threadIdx.x;
    const int wv   = tid >> 6;
    const int lane = tid & 63;
    const int quad = lane >> 4;
    const int l15  = lane & 15;

    // XCD-bijective swizzle (1568 = 8*196); o-tile pair adjacent -> L2 reuse.
    const int bid = blockIdx.x;
    const int swz = (bid & 7) * 196 + (bid >> 3);
    const int s0  = (swz >> 1) * 128;   // spatial tile
    const int o0  = (swz & 1) * 128;    // out-channel tile

    const int wo = (wv & 1) << 6;            // o half of wave tile
    const int wn = (wv >> 1) << 6;           // spatial half

    // tile-base padded slot (first pixel of tile, kh=0)
    const unsigned tb = (unsigned)s0 / HW_;
    const unsigned ttr = (unsigned)s0 - tb*HW_;
    const unsigned th = ttr / 56, twc = ttr - th*56;
    const size_t base0 = (size_t)(tb*HP_ + th)*WP_ + twc;

    // per-lane LDS read bases: chunk=quad, slot-delta of the lane's pixel for
    // fragment t (kh-independent; kw added as 16B immediate)
    int rA[4];
    #pragma unroll
    for (int t = 0; t < 4; ++t) {
        unsigned sp = (unsigned)(s0 + wn + t*16 + l15);
        unsigned b = sp / HW_, r = sp - b*HW_;
        unsigned h = r / 56,   w = r - h*56;
        unsigned slot = (b*HP_ + h)*WP_ + w;
        rA[t] = quad*4096 + (int)(slot - (unsigned)base0)*16;
    }

    const signed char* aBase = qwT2 + (size_t)quad*4096 + (size_t)(o0 + wo + l15)*16;

    int32x4 acc[4][4];
    #pragma unroll
    for (int i = 0; i < 4; ++i)
        #pragma unroll
        for (int j = 0; j < 4; ++j)
            acc[i][j] = (int32x4){0,0,0,0};

    int32x4 aP[4], aQ[4];

    // prologue: B(0), B(1) staged (8 loads), A(0,0) (4 loads) -> 12 in flight
    STAGEB(0);
    STAGEB(1);
    __builtin_amdgcn_sched_barrier(0);
    LOADA(0, 0, aP);
    __builtin_amdgcn_sched_barrier(0);

    SS(0,  aP, aQ)  SS(1,  aQ, aP)  SS(2,  aP, aQ)  SS(3,  aQ, aP)
    SS(4,  aP, aQ)  SS(5,  aQ, aP)  SS(6,  aP, aQ)  SS(7,  aQ, aP)
    SS(8,  aP, aQ)  SS(9,  aQ, aP)  SS(10, aP, aQ)  SS(11, aQ, aP)

    // rendezvous BEFORE any epilogue write to smem: SS(11) reads buf2, and
    // invS/biasS (33792..34816) alias buf2. Race fix for round-4 failure.
    __syncthreads();

    // ---- epilogue: LDS transpose -> full-line float4 stores ----
    float* lt    = (float*)smem;                   // [64][132] floats = 33792 B
    float* invS  = (float*)(smem + 33792);
    float* biasS = (float*)(smem + 34304);
    if (tid < 128) {
        float s = sw[o0 + tid];
        invS[tid]  = 1.0f / (s * sx[0]);
        biasS[tid] = bias[o0 + tid];
    }
    #pragma unroll
    for (int p = 0; p < 2; ++p) {
        __syncthreads();
        if ((wv & 1) == p) {
            #pragma unroll
            for (int mt = 0; mt < 4; ++mt)
                #pragma unroll
                for (int nt = 0; nt < 4; ++nt)
                    #pragma unroll
                    for (int r = 0; r < 4; ++r)
                        lt[(mt*16 + quad*4 + r)*132 + wn + nt*16 + l15]
                            = (float)acc[mt][nt][r];
        }
        __syncthreads();
        #pragma unroll
        for (int i = 0; i < 8; ++i) {
            int idx = i*256 + tid;                 // 2048 float4 chunks
            int o = idx >> 5;                      // 0..63
            int c = idx & 31;                      // sp/4 chunk
            float4 v = *(const float4*)&lt[o*132 + 4*c];
            int ol = p*64 + o;
            float is = invS[ol], bs = biasS[ol];
            unsigned sp = (unsigned)(s0 + 4*c);
            unsigned b  = sp / HW_;
            unsigned pos = sp - b*HW_;
            float4 wv4;
            wv4.x = fmaf(v.x, is, bs); wv4.y = fmaf(v.y, is, bs);
            wv4.z = fmaf(v.z, is, bs); wv4.w = fmaf(v.w, is, bs);
            *(float4*)(out + (size_t)b*CHW_ + (size_t)(o0 + ol)*HW_ + pos) = wv4;
        }
    }
}

extern "C" void kernel_launch(void* const* d_in, const int* in_sizes, int n_in,
                              void* d_out, int out_size, void* d_ws, size_t ws_size,
                              hipStream_t stream)
{
    (void)in_sizes; (void)n_in; (void)out_size; (void)ws_size;
    const float* x    = (const float*)d_in[0];
    const float* wgt  = (const float*)d_in[1];
    const float* bias = (const float*)d_in[2];
    const float* sw   = (const float*)d_in[3];
    const float* sx   = (const float*)d_in[4];
    float* out = (float*)d_out;

    signed char* qxp2 = (signed char*)d_ws;           // [cq][b][hp][wp][16]
    signed char* qwT2 = qxp2 + QXP_BYTES;             // [kk][cq][o][16]

    prep_kernel<<<2048, 256, 0, stream>>>(x, sx, wgt, sw, qxp2, qwT2);
    conv_kernel<<<1568, 256, 0, stream>>>(qxp2, qwT2, sw, bias, sx, out);
}